// Round 8
// baseline (201.209 us; speedup 1.0000x reference)
//
#include <hip/hip_runtime.h>

typedef unsigned long long u64;

// Problem constants (fixed by reference file)
#define N_TRUCK 100000
#define BLK 256
#define NB 256           // buckets per graph
#define NPB 391          // nodes per bucket: ceil(100000/256)
#define CAP 8192         // slots per bucket (mean 6250, sigma ~79)
#define PB 1024          // placer chunks (512-thread blocks, 4 blocks/CU)
#define BLK_PL 512       // place block size
#define BLK_P 1024       // deg/agg block size
#define CHUNK_MAX 1568   // >= ceil(E/PB)=1563
#define ROW_MASK 0x1FFFFu
#define LC_SHIFT 17

// ---------------- ws layout (bytes) ----------------
// curT i32[256] @ 0 (1024) | curC i32[256] @ 1024 (1024) | G f32[36] @ 2048
// dis_t @ 4096 | dis_c @ 404096 | s_t @ 804096 | y4 @ 1204096 (1600000)
// xs4 f32x4[100000] @ 2804096 (1600000)
// pT  u32[256*CAP] @ 4404096  (8388608)
// pC8 u64[256*CAP] @ 12792704 (16777216)  ends 29569920
#define WS_NEED_NEW 29569920ULL

// ============ place (+G on last block): 512 threads, 4 blocks/CU ============

__global__ __launch_bounds__(BLK_PL, 8)
void k_place(const int* __restrict__ trow, const int* __restrict__ tcol,
             const int* __restrict__ crow, const int* __restrict__ ccol,
             const float* __restrict__ ew, int E_,
             int* __restrict__ curT, int* __restrict__ curC,
             unsigned* __restrict__ pT, u64* __restrict__ pC8,
             const float* __restrict__ Wt, const float* __restrict__ bt,
             const float* __restrict__ Wc, const float* __restrict__ bc,
             const float* __restrict__ wlin, float* __restrict__ G) {
    if (blockIdx.x == PB) {
        int l = threadIdx.x;
        if (l < 64) {
            float acc[21];
#pragma unroll
            for (int k = 0; k < 21; k++) acc[k] = 0.0f;
            for (int h = l; h < 128; h += 64) {
                float m[6] = {Wt[h], bt[h], Wc[h], Wc[128 + h], Wc[256 + h], bc[h]};
                float w = wlin[h];
                int k = 0;
#pragma unroll
                for (int a = 0; a < 6; a++)
#pragma unroll
                    for (int b2 = a; b2 < 6; b2++)
                        acc[k++] += m[a] * m[b2] * w;
            }
            int k = 0;
#pragma unroll
            for (int a = 0; a < 6; a++)
#pragma unroll
                for (int b2 = a; b2 < 6; b2++) {
                    float v = acc[k++];
#pragma unroll
                    for (int off = 32; off; off >>= 1) v += __shfl_down(v, off);
                    if (l == 0) {
                        G[a * 6 + b2] = v;
                        G[b2 * 6 + a] = v;
                    }
                }
        }
        return;
    }

    __shared__ u64 pay8[CHUNK_MAX];          // car payload; truck reuses as u32[]
    __shared__ unsigned char bkt[CHUNK_MAX];
    __shared__ int hT[NB], hC[NB];           // persistent per-graph histograms
    __shared__ int shiftA[NB];
    __shared__ int wsum[8];
    unsigned* pay4 = (unsigned*)pay8;

    const int b = blockIdx.x;
    const int t = threadIdx.x;
    const int lane = t & 63, wv = t >> 6;
    const int chunk = (E_ + PB - 1) / PB;
    const int s0 = b * chunk, s1 = min(E_, s0 + chunk);
    const int n = s1 - s0;

    // -------- combined histogram (both graphs, one pass, 2 loads/iter) --------
    for (int k = t; k < NB; k += BLK_PL) { hT[k] = 0; hC[k] = 0; }
    __syncthreads();
    for (int j = s0 + t; j < s1; j += BLK_PL) {
        int tc = tcol[j];
        int cc = ccol[j];
        atomicAdd(&hT[tc / NPB], 1);
        atomicAdd(&hC[cc / NPB], 1);
    }
    __syncthreads();

    // -------- truck: scan hT, grab cursors, sort, flush --------
    {
        int cntk = 0, inc = 0;
        if (t < NB) {
            cntk = hT[t];
            inc = cntk;
#pragma unroll
            for (int off = 1; off < 64; off <<= 1) {
                int nv = __shfl_up(inc, off);
                if (lane >= off) inc += nv;
            }
            if (lane == 63) wsum[wv] = inc;
        }
        __syncthreads();
        if (t < 4) {
            int pv = wsum[t], pinc = pv;
#pragma unroll
            for (int off = 1; off < 4; off <<= 1) {
                int nv = __shfl_up(pinc, off);
                if (lane >= off) pinc += nv;
            }
            wsum[t] = pinc - pv;
        }
        __syncthreads();
        if (t < NB) {
            int lexcl = (inc - cntk) + wsum[wv];
            int gstart = t * CAP + atomicAdd(&curT[t], cntk);
            hT[t] = lexcl;                 // local cursor
            shiftA[t] = gstart - lexcl;    // flush shift
        }
        __syncthreads();
        for (int j = s0 + t; j < s1; j += BLK_PL) {
            int tc = tcol[j];
            int k = tc / NPB;
            int s = atomicAdd(&hT[k], 1);
            pay4[s] = ((unsigned)(tc - k * NPB) << LC_SHIFT) | (unsigned)trow[j];
            bkt[s] = (unsigned char)k;
        }
        __syncthreads();
        for (int s = t; s < n; s += BLK_PL)
            pT[s + shiftA[bkt[s]]] = pay4[s];
        __syncthreads();
    }

    // -------- car: scan hC, grab cursors, sort, flush --------
    {
        int cntk = 0, inc = 0;
        if (t < NB) {
            cntk = hC[t];
            inc = cntk;
#pragma unroll
            for (int off = 1; off < 64; off <<= 1) {
                int nv = __shfl_up(inc, off);
                if (lane >= off) inc += nv;
            }
            if (lane == 63) wsum[wv] = inc;
        }
        __syncthreads();
        if (t < 4) {
            int pv = wsum[t], pinc = pv;
#pragma unroll
            for (int off = 1; off < 4; off <<= 1) {
                int nv = __shfl_up(pinc, off);
                if (lane >= off) pinc += nv;
            }
            wsum[t] = pinc - pv;
        }
        __syncthreads();
        if (t < NB) {
            int lexcl = (inc - cntk) + wsum[wv];
            int gstart = t * CAP + atomicAdd(&curC[t], cntk);
            hC[t] = lexcl;
            shiftA[t] = gstart - lexcl;
        }
        __syncthreads();
        for (int j = s0 + t; j < s1; j += BLK_PL) {
            int cc = ccol[j];
            int k = cc / NPB;
            int s = atomicAdd(&hC[k], 1);
            unsigned lo = ((unsigned)(cc - k * NPB) << LC_SHIFT) | (unsigned)crow[j];
            pay8[s] = ((u64)__float_as_uint(ew[j]) << 32) | lo;
            bkt[s] = (unsigned char)k;
        }
        __syncthreads();
        for (int s = t; s < n; s += BLK_PL)
            pC8[s + shiftA[bkt[s]]] = pay8[s];
    }
}

// ============ per-bucket degree -> dis (+xs4 for car); 2*NB blocks, x4 ILP ============

__global__ __launch_bounds__(BLK_P, 8)
void k_deg2(const unsigned* __restrict__ pT, const u64* __restrict__ pC8,
            const int* __restrict__ curT, const int* __restrict__ curC,
            const float* __restrict__ x_car,
            float* __restrict__ dis_t, float* __restrict__ dis_c,
            float4* __restrict__ xs4, int nt, int nc) {
    __shared__ float acc[NPB];
    int b = blockIdx.x;
    bool car = b >= NB;
    int bk = car ? b - NB : b;
    int cnt = car ? curC[bk] : curT[bk];
    int base = bk * CAP;
    for (int k = threadIdx.x; k < NPB; k += BLK_P) acc[k] = 0.0f;
    __syncthreads();
    if (car) {
        const ulonglong4* p4 = (const ulonglong4*)(pC8 + base);
        int q = cnt >> 2;
        for (int j = threadIdx.x; j < q; j += BLK_P) {
            ulonglong4 v = p4[j];
            atomicAdd(&acc[((unsigned)v.x) >> LC_SHIFT], __uint_as_float((unsigned)(v.x >> 32)));
            atomicAdd(&acc[((unsigned)v.y) >> LC_SHIFT], __uint_as_float((unsigned)(v.y >> 32)));
            atomicAdd(&acc[((unsigned)v.z) >> LC_SHIFT], __uint_as_float((unsigned)(v.z >> 32)));
            atomicAdd(&acc[((unsigned)v.w) >> LC_SHIFT], __uint_as_float((unsigned)(v.w >> 32)));
        }
        for (int j = (q << 2) + threadIdx.x; j < cnt; j += BLK_P) {
            u64 v = pC8[base + j];
            atomicAdd(&acc[((unsigned)v) >> LC_SHIFT], __uint_as_float((unsigned)(v >> 32)));
        }
    } else {
        const uint4* p4 = (const uint4*)(pT + base);
        int q = cnt >> 2;
        for (int j = threadIdx.x; j < q; j += BLK_P) {
            uint4 v = p4[j];
            atomicAdd(&acc[v.x >> LC_SHIFT], 1.0f);
            atomicAdd(&acc[v.y >> LC_SHIFT], 1.0f);
            atomicAdd(&acc[v.z >> LC_SHIFT], 1.0f);
            atomicAdd(&acc[v.w >> LC_SHIFT], 1.0f);
        }
        for (int j = (q << 2) + threadIdx.x; j < cnt; j += BLK_P)
            atomicAdd(&acc[pT[base + j] >> LC_SHIFT], 1.0f);
    }
    __syncthreads();
    int ntot = car ? nc : nt;
    for (int nn = threadIdx.x; nn < NPB; nn += BLK_P) {
        int node = bk * NPB + nn;
        if (node < ntot) {
            float d = rsqrtf(acc[nn] + 1.0f);
            if (car) {
                dis_c[node] = d;
                const float* xn = &x_car[3 * node];
                xs4[node] = make_float4(d * xn[0], d * xn[1], d * xn[2], d);
            } else {
                dis_t[node] = d;
            }
        }
    }
}

// ============ per-bucket aggregation -> s_t / y4; 2*NB blocks, x4 ILP ============

__global__ __launch_bounds__(BLK_P, 8)
void k_agg(const unsigned* __restrict__ pT, const u64* __restrict__ pC8,
           const int* __restrict__ curT, const int* __restrict__ curC,
           const float* __restrict__ dis_t, const float* __restrict__ dis_c,
           const float4* __restrict__ xs4,
           float* __restrict__ s_t, float4* __restrict__ y4,
           int nt, int nc) {
    int b = blockIdx.x;
    if (b < NB) {
        __shared__ float sacc[NPB];
        int cnt = curT[b];
        int base = b * CAP;
        for (int k = threadIdx.x; k < NPB; k += BLK_P) sacc[k] = 0.0f;
        __syncthreads();
        const uint4* p4 = (const uint4*)(pT + base);
        int q = cnt >> 2;
        for (int j = threadIdx.x; j < q; j += BLK_P) {
            uint4 v = p4[j];
            float d0 = dis_t[v.x & ROW_MASK];
            float d1 = dis_t[v.y & ROW_MASK];
            float d2 = dis_t[v.z & ROW_MASK];
            float d3 = dis_t[v.w & ROW_MASK];
            atomicAdd(&sacc[v.x >> LC_SHIFT], d0);
            atomicAdd(&sacc[v.y >> LC_SHIFT], d1);
            atomicAdd(&sacc[v.z >> LC_SHIFT], d2);
            atomicAdd(&sacc[v.w >> LC_SHIFT], d3);
        }
        for (int j = (q << 2) + threadIdx.x; j < cnt; j += BLK_P) {
            unsigned v = pT[base + j];
            atomicAdd(&sacc[v >> LC_SHIFT], dis_t[v & ROW_MASK]);
        }
        __syncthreads();
        for (int nn = threadIdx.x; nn < NPB; nn += BLK_P) {
            int node = b * NPB + nn;
            if (node < nt) {
                float d = dis_t[node];
                s_t[node] = fmaf(d, sacc[nn], d * d);
            }
        }
    } else {
        int bk = b - NB;
        __shared__ float y[NPB * 5];   // stride 5: avoid stride-4 bank aliasing
        __shared__ float dcl[NPB];
        int cnt = curC[bk];
        int base = bk * CAP;
        for (int k = threadIdx.x; k < NPB * 5; k += BLK_P) y[k] = 0.0f;
        for (int k = threadIdx.x; k < NPB; k += BLK_P) {
            int node = bk * NPB + k;
            dcl[k] = (node < nc) ? dis_c[node] : 0.0f;
        }
        __syncthreads();
        const ulonglong4* p4 = (const ulonglong4*)(pC8 + base);
        int q = cnt >> 2;
        for (int j = threadIdx.x; j < q; j += BLK_P) {
            ulonglong4 v = p4[j];
            unsigned lo0 = (unsigned)v.x, lo1 = (unsigned)v.y;
            unsigned lo2 = (unsigned)v.z, lo3 = (unsigned)v.w;
            float4 x0 = xs4[lo0 & ROW_MASK];
            float4 x1 = xs4[lo1 & ROW_MASK];
            float4 x2 = xs4[lo2 & ROW_MASK];
            float4 x3 = xs4[lo3 & ROW_MASK];
            int c0 = lo0 >> LC_SHIFT, c1 = lo1 >> LC_SHIFT;
            int c2 = lo2 >> LC_SHIFT, c3 = lo3 >> LC_SHIFT;
            float n0 = __uint_as_float((unsigned)(v.x >> 32)) * dcl[c0];
            float n1 = __uint_as_float((unsigned)(v.y >> 32)) * dcl[c1];
            float n2 = __uint_as_float((unsigned)(v.z >> 32)) * dcl[c2];
            float n3 = __uint_as_float((unsigned)(v.w >> 32)) * dcl[c3];
            atomicAdd(&y[c0 * 5 + 0], n0 * x0.x);
            atomicAdd(&y[c0 * 5 + 1], n0 * x0.y);
            atomicAdd(&y[c0 * 5 + 2], n0 * x0.z);
            atomicAdd(&y[c1 * 5 + 0], n1 * x1.x);
            atomicAdd(&y[c1 * 5 + 1], n1 * x1.y);
            atomicAdd(&y[c1 * 5 + 2], n1 * x1.z);
            atomicAdd(&y[c2 * 5 + 0], n2 * x2.x);
            atomicAdd(&y[c2 * 5 + 1], n2 * x2.y);
            atomicAdd(&y[c2 * 5 + 2], n2 * x2.z);
            atomicAdd(&y[c3 * 5 + 0], n3 * x3.x);
            atomicAdd(&y[c3 * 5 + 1], n3 * x3.y);
            atomicAdd(&y[c3 * 5 + 2], n3 * x3.z);
        }
        for (int j = (q << 2) + threadIdx.x; j < cnt; j += BLK_P) {
            u64 v = pC8[base + j];
            unsigned lo = (unsigned)v;
            float4 xa = xs4[lo & ROW_MASK];
            int lc = lo >> LC_SHIFT;
            float na = __uint_as_float((unsigned)(v >> 32)) * dcl[lc];
            atomicAdd(&y[lc * 5 + 0], na * xa.x);
            atomicAdd(&y[lc * 5 + 1], na * xa.y);
            atomicAdd(&y[lc * 5 + 2], na * xa.z);
        }
        __syncthreads();
        for (int nn = threadIdx.x; nn < NPB; nn += BLK_P) {
            int node = bk * NPB + nn;
            if (node < nc) {
                float d = dcl[nn];
                float4 xs = xs4[node];           // d*x already
                y4[node] = make_float4(fmaf(d, xs.x, y[nn * 5 + 0]),
                                       fmaf(d, xs.y, y[nn * 5 + 1]),
                                       fmaf(d, xs.z, y[nn * 5 + 2]), 1.0f);
            }
        }
    }
}

// ============ pair scorer ============

__device__ __forceinline__ void load_zf(int i, const float* __restrict__ s_t,
                                        const float4* __restrict__ y4, float z[6]) {
    if (i < N_TRUCK) {
        z[0] = s_t[i]; z[1] = 1.0f; z[2] = 0.0f; z[3] = 0.0f; z[4] = 0.0f; z[5] = 0.0f;
    } else {
        float4 y = y4[i - N_TRUCK];
        z[0] = 0.0f; z[1] = 0.0f; z[2] = y.x; z[3] = y.y; z[4] = y.z; z[5] = 1.0f;
    }
}

__global__ void k_pairs(const int* __restrict__ src, const int* __restrict__ dst, int P_,
                        const float* __restrict__ s_t, const float4* __restrict__ y4,
                        const float* __restrict__ G, const float* __restrict__ b_lin,
                        float* __restrict__ out) {
    int p = blockIdx.x * blockDim.x + threadIdx.x;
    if (p >= P_) return;
    float zs[6], zd[6];
    load_zf(src[p], s_t, y4, zs);
    load_zf(dst[p], s_t, y4, zd);
    float acc = 0.0f;
#pragma unroll
    for (int a = 0; a < 6; a++) {
        float g = 0.0f;
#pragma unroll
        for (int b = 0; b < 6; b++) g = fmaf(G[a * 6 + b], zd[b], g);
        acc = fmaf(zs[a], g, acc);
    }
    out[p] = acc + b_lin[0];
}

// ============ round-1 fallback (global-atomic path) ============

__global__ void k_G(const float* __restrict__ Wt, const float* __restrict__ bt,
                    const float* __restrict__ Wc, const float* __restrict__ bc,
                    const float* __restrict__ wlin, float* __restrict__ G) {
    int l = threadIdx.x;
    float acc[21];
#pragma unroll
    for (int k = 0; k < 21; k++) acc[k] = 0.0f;
    for (int h = l; h < 128; h += 64) {
        float m[6] = {Wt[h], bt[h], Wc[h], Wc[128 + h], Wc[256 + h], bc[h]};
        float w = wlin[h];
        int k = 0;
#pragma unroll
        for (int a = 0; a < 6; a++)
#pragma unroll
            for (int b = a; b < 6; b++)
                acc[k++] += m[a] * m[b] * w;
    }
    int k = 0;
#pragma unroll
    for (int a = 0; a < 6; a++)
#pragma unroll
        for (int b = a; b < 6; b++) {
            float v = acc[k++];
#pragma unroll
            for (int off = 32; off; off >>= 1) v += __shfl_down(v, off);
            if (l == 0) {
                G[a * 6 + b] = v;
                G[b * 6 + a] = v;
            }
        }
}

__global__ void k_deg(const int* __restrict__ tcol, const int* __restrict__ ccol,
                      const float* __restrict__ ew, int E_,
                      int* __restrict__ cnt_t, float* __restrict__ degw_c) {
    int i = blockIdx.x * blockDim.x + threadIdx.x;
    if (i >= E_) return;
    atomicAdd(&cnt_t[tcol[i]], 1);
    atomicAdd(&degw_c[ccol[i]], ew[i]);
}

__global__ void k_dis(const int* __restrict__ cnt_t, const float* __restrict__ degw_c,
                      float* __restrict__ dis_t, float* __restrict__ dis_c,
                      int nt, int nc) {
    int i = blockIdx.x * blockDim.x + threadIdx.x;
    if (i < nt) dis_t[i] = rsqrtf((float)cnt_t[i] + 1.0f);
    if (i < nc) dis_c[i] = rsqrtf(degw_c[i] + 1.0f);
}

__global__ void k_scat(const int* __restrict__ trow, const int* __restrict__ tcol,
                       const int* __restrict__ crow, const int* __restrict__ ccol,
                       const float* __restrict__ ew, int E_,
                       const float* __restrict__ dis_t, const float* __restrict__ dis_c,
                       const float* __restrict__ x_car,
                       float* __restrict__ sumdis, float* __restrict__ y4) {
    int i = blockIdx.x * blockDim.x + threadIdx.x;
    if (i >= E_) return;
    atomicAdd(&sumdis[tcol[i]], dis_t[trow[i]]);
    int r = crow[i], c = ccol[i];
    float nrm = dis_c[r] * ew[i] * dis_c[c];
    atomicAdd(&y4[c * 4 + 0], nrm * x_car[r * 3 + 0]);
    atomicAdd(&y4[c * 4 + 1], nrm * x_car[r * 3 + 1]);
    atomicAdd(&y4[c * 4 + 2], nrm * x_car[r * 3 + 2]);
}

__global__ void k_fin(int nt, int nc,
                      const float* __restrict__ dis_t, const float* __restrict__ sumdis,
                      float* __restrict__ s_t,
                      const float* __restrict__ dis_c, const float* __restrict__ x_car,
                      float* __restrict__ y4) {
    int i = blockIdx.x * blockDim.x + threadIdx.x;
    if (i < nt) {
        float d = dis_t[i];
        s_t[i] = d * sumdis[i] + d * d;
    }
    if (i < nc) {
        float d2 = dis_c[i] * dis_c[i];
        y4[i * 4 + 0] += d2 * x_car[i * 3 + 0];
        y4[i * 4 + 1] += d2 * x_car[i * 3 + 1];
        y4[i * 4 + 2] += d2 * x_car[i * 3 + 2];
        y4[i * 4 + 3] = 1.0f;
    }
}

// ============ launch ============

extern "C" void kernel_launch(void* const* d_in, const int* in_sizes, int n_in,
                              void* d_out, int out_size, void* d_ws, size_t ws_size,
                              hipStream_t stream) {
    const float* x_car  = (const float*)d_in[0];
    const int*   ei_t   = (const int*)d_in[1];
    const int*   ei_c   = (const int*)d_in[2];
    const float* ew_c   = (const float*)d_in[3];
    const int*   src    = (const int*)d_in[4];
    const int*   dst    = (const int*)d_in[5];
    const float* W_t    = (const float*)d_in[7];
    const float* b_t    = (const float*)d_in[8];
    const float* W_c    = (const float*)d_in[9];
    const float* b_c    = (const float*)d_in[10];
    const float* W_lin  = (const float*)d_in[11];
    const float* b_lin  = (const float*)d_in[12];
    float* out = (float*)d_out;

    const int NC = in_sizes[0] / 3;   // 100000
    const int E_ = in_sizes[1] / 2;   // 1600000
    const int P_ = in_sizes[4];       // 200000

    const int* trow = ei_t;  const int* tcol = ei_t + E_;
    const int* crow = ei_c;  const int* ccol = ei_c + E_;

    char* ws = (char*)d_ws;
    int gP = (P_ + BLK - 1) / BLK;
    int chunk = (E_ + PB - 1) / PB;

    if (ws_size >= WS_NEED_NEW && chunk <= CHUNK_MAX && NB * NPB >= N_TRUCK &&
        NB * NPB >= NC && NB * CAP >= E_ + 8192) {
        int*      curT  = (int*)(ws + 0);
        int*      curC  = (int*)(ws + 1024);
        float*    G     = (float*)(ws + 2048);
        float*    dis_t = (float*)(ws + 4096);
        float*    dis_c = (float*)(ws + 404096);
        float*    s_t   = (float*)(ws + 804096);
        float*    y4    = (float*)(ws + 1204096);
        float4*   xs4   = (float4*)(ws + 2804096);
        unsigned* pT    = (unsigned*)(ws + 4404096);
        u64*      pC8   = (u64*)(ws + 12792704);

        hipMemsetAsync(ws, 0, 2048, stream);   // cursors
        k_place<<<PB + 1, BLK_PL, 0, stream>>>(trow, tcol, crow, ccol, ew_c, E_,
                                               curT, curC, pT, pC8,
                                               W_t, b_t, W_c, b_c, W_lin, G);
        k_deg2<<<2 * NB, BLK_P, 0, stream>>>(pT, pC8, curT, curC, x_car,
                                             dis_t, dis_c, xs4, N_TRUCK, NC);
        k_agg<<<2 * NB, BLK_P, 0, stream>>>(pT, pC8, curT, curC, dis_t, dis_c,
                                            xs4, s_t, (float4*)y4, N_TRUCK, NC);
        k_pairs<<<gP, BLK, 0, stream>>>(src, dst, P_, s_t, (const float4*)y4, G, b_lin, out);
    } else {
        // round-1 global-atomic fallback (~4 MB ws)
        int*   cnt_t  = (int*)(ws + 0);
        float* sumdis = (float*)(ws + 400000);
        float* degw_c = (float*)(ws + 800000);
        float* y4     = (float*)(ws + 1200000);
        float* dis_t  = (float*)(ws + 2800000);
        float* dis_c  = (float*)(ws + 3200000);
        float* s_t    = (float*)(ws + 3600000);
        float* G      = (float*)(ws + 4000000);

        hipMemsetAsync(ws, 0, 2800000, stream);
        int gE = (E_ + BLK - 1) / BLK;
        int gN = ((N_TRUCK > NC ? N_TRUCK : NC) + BLK - 1) / BLK;
        k_deg<<<gE, BLK, 0, stream>>>(tcol, ccol, ew_c, E_, cnt_t, degw_c);
        k_dis<<<gN, BLK, 0, stream>>>(cnt_t, degw_c, dis_t, dis_c, N_TRUCK, NC);
        k_scat<<<gE, BLK, 0, stream>>>(trow, tcol, crow, ccol, ew_c, E_,
                                       dis_t, dis_c, x_car, sumdis, y4);
        k_fin<<<gN, BLK, 0, stream>>>(N_TRUCK, NC, dis_t, sumdis, s_t, dis_c, x_car, y4);
        k_G<<<1, 64, 0, stream>>>(W_t, b_t, W_c, b_c, W_lin, G);
        k_pairs<<<gP, BLK, 0, stream>>>(src, dst, P_, s_t, (const float4*)y4, G, b_lin, out);
    }
}

// Round 9
// 185.351 us; speedup vs baseline: 1.0856x; 1.0856x over previous
//
#include <hip/hip_runtime.h>

typedef unsigned long long u64;

// Problem constants (fixed by reference file)
#define N_TRUCK 100000
#define BLK 256
#define NB 256           // buckets per graph
#define NPB 391          // nodes per bucket: ceil(100000/256)
#define CAP 8192         // slots per bucket (mean 6250, sigma ~79)
#define PB 512           // placer chunks (512-thread blocks, 4 blocks/CU, run len ~24)
#define BLK_PL 512       // place block size
#define BLK_P 1024       // deg/agg block size
#define CHUNK_MAX 3136   // >= ceil(E/PB)=3125
#define ROW_MASK 0x1FFFFu
#define LC_SHIFT 17

// ---------------- ws layout (bytes) ----------------
// curT i32[256] @ 0 (1024) | curC i32[256] @ 1024 (1024) | G f32[36] @ 2048
// dis_t @ 4096 | dis_c @ 404096 | s_t @ 804096 | y4 @ 1204096 (1600000)
// xs4 f32x4[100000] @ 2804096 (1600000)
// pT  u32[256*CAP] @ 4404096  (8388608)
// pC8 u64[256*CAP] @ 12792704 (16777216)  ends 29569920
#define WS_NEED_NEW 29569920ULL

// ============ place (+G on last block): 512 thr, chunk 3125, 4 blocks/CU ============

__global__ __launch_bounds__(BLK_PL, 8)
void k_place(const int* __restrict__ trow, const int* __restrict__ tcol,
             const int* __restrict__ crow, const int* __restrict__ ccol,
             const float* __restrict__ ew, int E_,
             int* __restrict__ curT, int* __restrict__ curC,
             unsigned* __restrict__ pT, u64* __restrict__ pC8,
             const float* __restrict__ Wt, const float* __restrict__ bt,
             const float* __restrict__ Wc, const float* __restrict__ bc,
             const float* __restrict__ wlin, float* __restrict__ G) {
    if (blockIdx.x == PB) {
        int l = threadIdx.x;
        if (l < 64) {
            float acc[21];
#pragma unroll
            for (int k = 0; k < 21; k++) acc[k] = 0.0f;
            for (int h = l; h < 128; h += 64) {
                float m[6] = {Wt[h], bt[h], Wc[h], Wc[128 + h], Wc[256 + h], bc[h]};
                float w = wlin[h];
                int k = 0;
#pragma unroll
                for (int a = 0; a < 6; a++)
#pragma unroll
                    for (int b2 = a; b2 < 6; b2++)
                        acc[k++] += m[a] * m[b2] * w;
            }
            int k = 0;
#pragma unroll
            for (int a = 0; a < 6; a++)
#pragma unroll
                for (int b2 = a; b2 < 6; b2++) {
                    float v = acc[k++];
#pragma unroll
                    for (int off = 32; off; off >>= 1) v += __shfl_down(v, off);
                    if (l == 0) {
                        G[a * 6 + b2] = v;
                        G[b2 * 6 + a] = v;
                    }
                }
        }
        return;
    }

    __shared__ u64 pay8[CHUNK_MAX];          // car payload; truck reuses as u32[]
    __shared__ unsigned char bkt[CHUNK_MAX];
    __shared__ int hT[NB], hC[NB];           // persistent per-graph histograms
    __shared__ int shiftA[NB];
    __shared__ int wsum[8];
    unsigned* pay4 = (unsigned*)pay8;

    const int b = blockIdx.x;
    const int t = threadIdx.x;
    const int lane = t & 63, wv = t >> 6;
    const int chunk = (E_ + PB - 1) / PB;
    const int s0 = b * chunk, s1 = min(E_, s0 + chunk);
    const int n = s1 - s0;

    // -------- combined histogram (both graphs, one pass) --------
    for (int k = t; k < NB; k += BLK_PL) { hT[k] = 0; hC[k] = 0; }
    __syncthreads();
    for (int j = s0 + t; j < s1; j += BLK_PL) {
        int tc = tcol[j];
        int cc = ccol[j];
        atomicAdd(&hT[tc / NPB], 1);
        atomicAdd(&hC[cc / NPB], 1);
    }
    __syncthreads();

    // -------- truck: scan hT, grab cursors, sort, flush --------
    {
        int cntk = 0, inc = 0;
        if (t < NB) {
            cntk = hT[t];
            inc = cntk;
#pragma unroll
            for (int off = 1; off < 64; off <<= 1) {
                int nv = __shfl_up(inc, off);
                if (lane >= off) inc += nv;
            }
            if (lane == 63) wsum[wv] = inc;
        }
        __syncthreads();
        if (t < 4) {
            int pv = wsum[t], pinc = pv;
#pragma unroll
            for (int off = 1; off < 4; off <<= 1) {
                int nv = __shfl_up(pinc, off);
                if (lane >= off) pinc += nv;
            }
            wsum[t] = pinc - pv;
        }
        __syncthreads();
        if (t < NB) {
            int lexcl = (inc - cntk) + wsum[wv];
            int gstart = t * CAP + atomicAdd(&curT[t], cntk);
            hT[t] = lexcl;                 // local cursor
            shiftA[t] = gstart - lexcl;    // flush shift
        }
        __syncthreads();
        for (int j = s0 + t; j < s1; j += BLK_PL) {
            int tc = tcol[j];
            int k = tc / NPB;
            int s = atomicAdd(&hT[k], 1);
            pay4[s] = ((unsigned)(tc - k * NPB) << LC_SHIFT) | (unsigned)trow[j];
            bkt[s] = (unsigned char)k;
        }
        __syncthreads();
        for (int s = t; s < n; s += BLK_PL)
            pT[s + shiftA[bkt[s]]] = pay4[s];
        __syncthreads();
    }

    // -------- car: scan hC, grab cursors, sort, flush --------
    {
        int cntk = 0, inc = 0;
        if (t < NB) {
            cntk = hC[t];
            inc = cntk;
#pragma unroll
            for (int off = 1; off < 64; off <<= 1) {
                int nv = __shfl_up(inc, off);
                if (lane >= off) inc += nv;
            }
            if (lane == 63) wsum[wv] = inc;
        }
        __syncthreads();
        if (t < 4) {
            int pv = wsum[t], pinc = pv;
#pragma unroll
            for (int off = 1; off < 4; off <<= 1) {
                int nv = __shfl_up(pinc, off);
                if (lane >= off) pinc += nv;
            }
            wsum[t] = pinc - pv;
        }
        __syncthreads();
        if (t < NB) {
            int lexcl = (inc - cntk) + wsum[wv];
            int gstart = t * CAP + atomicAdd(&curC[t], cntk);
            hC[t] = lexcl;
            shiftA[t] = gstart - lexcl;
        }
        __syncthreads();
        for (int j = s0 + t; j < s1; j += BLK_PL) {
            int cc = ccol[j];
            int k = cc / NPB;
            int s = atomicAdd(&hC[k], 1);
            unsigned lo = ((unsigned)(cc - k * NPB) << LC_SHIFT) | (unsigned)crow[j];
            pay8[s] = ((u64)__float_as_uint(ew[j]) << 32) | lo;
            bkt[s] = (unsigned char)k;
        }
        __syncthreads();
        for (int s = t; s < n; s += BLK_PL)
            pC8[s + shiftA[bkt[s]]] = pay8[s];
    }
}

// ============ per-bucket degree -> dis (+xs4 for car); 2*NB blocks (round-6 proven) ============

__global__ void k_deg2(const unsigned* __restrict__ pT, const u64* __restrict__ pC8,
                       const int* __restrict__ curT, const int* __restrict__ curC,
                       const float* __restrict__ x_car,
                       float* __restrict__ dis_t, float* __restrict__ dis_c,
                       float4* __restrict__ xs4, int nt, int nc) {
    __shared__ float acc[NPB];
    int b = blockIdx.x;
    bool car = b >= NB;
    int bk = car ? b - NB : b;
    int cnt = car ? curC[bk] : curT[bk];
    int s0 = bk * CAP;
    for (int k = threadIdx.x; k < NPB; k += blockDim.x) acc[k] = 0.0f;
    __syncthreads();
    if (car) {
        const ulonglong2* p2 = (const ulonglong2*)(pC8 + s0);
        int half = cnt >> 1;
        for (int j = threadIdx.x; j < half; j += blockDim.x) {
            ulonglong2 v = p2[j];
            atomicAdd(&acc[((unsigned)v.x) >> LC_SHIFT], __uint_as_float((unsigned)(v.x >> 32)));
            atomicAdd(&acc[((unsigned)v.y) >> LC_SHIFT], __uint_as_float((unsigned)(v.y >> 32)));
        }
        if ((cnt & 1) && threadIdx.x == 0) {
            u64 v = pC8[s0 + cnt - 1];
            atomicAdd(&acc[((unsigned)v) >> LC_SHIFT], __uint_as_float((unsigned)(v >> 32)));
        }
    } else {
        const uint2* p2 = (const uint2*)(pT + s0);
        int half = cnt >> 1;
        for (int j = threadIdx.x; j < half; j += blockDim.x) {
            uint2 v = p2[j];
            atomicAdd(&acc[v.x >> LC_SHIFT], 1.0f);
            atomicAdd(&acc[v.y >> LC_SHIFT], 1.0f);
        }
        if ((cnt & 1) && threadIdx.x == 0)
            atomicAdd(&acc[pT[s0 + cnt - 1] >> LC_SHIFT], 1.0f);
    }
    __syncthreads();
    int ntot = car ? nc : nt;
    for (int nn = threadIdx.x; nn < NPB; nn += blockDim.x) {
        int node = bk * NPB + nn;
        if (node < ntot) {
            float d = rsqrtf(acc[nn] + 1.0f);
            if (car) {
                dis_c[node] = d;
                const float* xn = &x_car[3 * node];
                xs4[node] = make_float4(d * xn[0], d * xn[1], d * xn[2], d);
            } else {
                dis_t[node] = d;
            }
        }
    }
}

// ============ per-bucket aggregation -> s_t / y4; 2*NB blocks (round-6 proven) ============

__global__ void k_agg(const unsigned* __restrict__ pT, const u64* __restrict__ pC8,
                      const int* __restrict__ curT, const int* __restrict__ curC,
                      const float* __restrict__ dis_t, const float* __restrict__ dis_c,
                      const float4* __restrict__ xs4,
                      float* __restrict__ s_t, float4* __restrict__ y4,
                      int nt, int nc) {
    int b = blockIdx.x;
    if (b < NB) {
        __shared__ float sacc[NPB];
        int cnt = curT[b];
        int s0 = b * CAP;
        for (int k = threadIdx.x; k < NPB; k += blockDim.x) sacc[k] = 0.0f;
        __syncthreads();
        const uint2* p2 = (const uint2*)(pT + s0);
        int half = cnt >> 1;
        for (int j = threadIdx.x; j < half; j += blockDim.x) {
            uint2 v = p2[j];
            float da = dis_t[v.x & ROW_MASK];
            float db = dis_t[v.y & ROW_MASK];
            atomicAdd(&sacc[v.x >> LC_SHIFT], da);
            atomicAdd(&sacc[v.y >> LC_SHIFT], db);
        }
        if ((cnt & 1) && threadIdx.x == 0) {
            unsigned v = pT[s0 + cnt - 1];
            atomicAdd(&sacc[v >> LC_SHIFT], dis_t[v & ROW_MASK]);
        }
        __syncthreads();
        for (int nn = threadIdx.x; nn < NPB; nn += blockDim.x) {
            int node = b * NPB + nn;
            if (node < nt) {
                float d = dis_t[node];
                s_t[node] = fmaf(d, sacc[nn], d * d);
            }
        }
    } else {
        int bk = b - NB;
        __shared__ float y[NPB * 5];   // stride 5: avoid stride-4 bank aliasing
        __shared__ float dcl[NPB];
        int cnt = curC[bk];
        int s0 = bk * CAP;
        for (int k = threadIdx.x; k < NPB * 5; k += blockDim.x) y[k] = 0.0f;
        for (int k = threadIdx.x; k < NPB; k += blockDim.x) {
            int node = bk * NPB + k;
            dcl[k] = (node < nc) ? dis_c[node] : 0.0f;
        }
        __syncthreads();
        const ulonglong2* p2 = (const ulonglong2*)(pC8 + s0);
        int half = cnt >> 1;
        for (int j = threadIdx.x; j < half; j += blockDim.x) {
            ulonglong2 v = p2[j];
            unsigned loa = (unsigned)v.x, lob = (unsigned)v.y;
            float4 xa = xs4[loa & ROW_MASK];     // dis_c[r] pre-folded
            float4 xb = xs4[lob & ROW_MASK];
            int lca = loa >> LC_SHIFT, lcb = lob >> LC_SHIFT;
            float na = __uint_as_float((unsigned)(v.x >> 32)) * dcl[lca];
            float nb = __uint_as_float((unsigned)(v.y >> 32)) * dcl[lcb];
            atomicAdd(&y[lca * 5 + 0], na * xa.x);
            atomicAdd(&y[lca * 5 + 1], na * xa.y);
            atomicAdd(&y[lca * 5 + 2], na * xa.z);
            atomicAdd(&y[lcb * 5 + 0], nb * xb.x);
            atomicAdd(&y[lcb * 5 + 1], nb * xb.y);
            atomicAdd(&y[lcb * 5 + 2], nb * xb.z);
        }
        if ((cnt & 1) && threadIdx.x == 0) {
            u64 v = pC8[s0 + cnt - 1];
            unsigned lo = (unsigned)v;
            float4 xa = xs4[lo & ROW_MASK];
            int lc = lo >> LC_SHIFT;
            float na = __uint_as_float((unsigned)(v >> 32)) * dcl[lc];
            atomicAdd(&y[lc * 5 + 0], na * xa.x);
            atomicAdd(&y[lc * 5 + 1], na * xa.y);
            atomicAdd(&y[lc * 5 + 2], na * xa.z);
        }
        __syncthreads();
        for (int nn = threadIdx.x; nn < NPB; nn += blockDim.x) {
            int node = bk * NPB + nn;
            if (node < nc) {
                float d = dcl[nn];
                float4 xs = xs4[node];           // d*x already
                y4[node] = make_float4(fmaf(d, xs.x, y[nn * 5 + 0]),
                                       fmaf(d, xs.y, y[nn * 5 + 1]),
                                       fmaf(d, xs.z, y[nn * 5 + 2]), 1.0f);
            }
        }
    }
}

// ============ pair scorer ============

__device__ __forceinline__ void load_zf(int i, const float* __restrict__ s_t,
                                        const float4* __restrict__ y4, float z[6]) {
    if (i < N_TRUCK) {
        z[0] = s_t[i]; z[1] = 1.0f; z[2] = 0.0f; z[3] = 0.0f; z[4] = 0.0f; z[5] = 0.0f;
    } else {
        float4 y = y4[i - N_TRUCK];
        z[0] = 0.0f; z[1] = 0.0f; z[2] = y.x; z[3] = y.y; z[4] = y.z; z[5] = 1.0f;
    }
}

__global__ void k_pairs(const int* __restrict__ src, const int* __restrict__ dst, int P_,
                        const float* __restrict__ s_t, const float4* __restrict__ y4,
                        const float* __restrict__ G, const float* __restrict__ b_lin,
                        float* __restrict__ out) {
    int p = blockIdx.x * blockDim.x + threadIdx.x;
    if (p >= P_) return;
    float zs[6], zd[6];
    load_zf(src[p], s_t, y4, zs);
    load_zf(dst[p], s_t, y4, zd);
    float acc = 0.0f;
#pragma unroll
    for (int a = 0; a < 6; a++) {
        float g = 0.0f;
#pragma unroll
        for (int b = 0; b < 6; b++) g = fmaf(G[a * 6 + b], zd[b], g);
        acc = fmaf(zs[a], g, acc);
    }
    out[p] = acc + b_lin[0];
}

// ============ round-1 fallback (global-atomic path) ============

__global__ void k_G(const float* __restrict__ Wt, const float* __restrict__ bt,
                    const float* __restrict__ Wc, const float* __restrict__ bc,
                    const float* __restrict__ wlin, float* __restrict__ G) {
    int l = threadIdx.x;
    float acc[21];
#pragma unroll
    for (int k = 0; k < 21; k++) acc[k] = 0.0f;
    for (int h = l; h < 128; h += 64) {
        float m[6] = {Wt[h], bt[h], Wc[h], Wc[128 + h], Wc[256 + h], bc[h]};
        float w = wlin[h];
        int k = 0;
#pragma unroll
        for (int a = 0; a < 6; a++)
#pragma unroll
            for (int b = a; b < 6; b++)
                acc[k++] += m[a] * m[b] * w;
    }
    int k = 0;
#pragma unroll
    for (int a = 0; a < 6; a++)
#pragma unroll
        for (int b = a; b < 6; b++) {
            float v = acc[k++];
#pragma unroll
            for (int off = 32; off; off >>= 1) v += __shfl_down(v, off);
            if (l == 0) {
                G[a * 6 + b] = v;
                G[b * 6 + a] = v;
            }
        }
}

__global__ void k_deg(const int* __restrict__ tcol, const int* __restrict__ ccol,
                      const float* __restrict__ ew, int E_,
                      int* __restrict__ cnt_t, float* __restrict__ degw_c) {
    int i = blockIdx.x * blockDim.x + threadIdx.x;
    if (i >= E_) return;
    atomicAdd(&cnt_t[tcol[i]], 1);
    atomicAdd(&degw_c[ccol[i]], ew[i]);
}

__global__ void k_dis(const int* __restrict__ cnt_t, const float* __restrict__ degw_c,
                      float* __restrict__ dis_t, float* __restrict__ dis_c,
                      int nt, int nc) {
    int i = blockIdx.x * blockDim.x + threadIdx.x;
    if (i < nt) dis_t[i] = rsqrtf((float)cnt_t[i] + 1.0f);
    if (i < nc) dis_c[i] = rsqrtf(degw_c[i] + 1.0f);
}

__global__ void k_scat(const int* __restrict__ trow, const int* __restrict__ tcol,
                       const int* __restrict__ crow, const int* __restrict__ ccol,
                       const float* __restrict__ ew, int E_,
                       const float* __restrict__ dis_t, const float* __restrict__ dis_c,
                       const float* __restrict__ x_car,
                       float* __restrict__ sumdis, float* __restrict__ y4) {
    int i = blockIdx.x * blockDim.x + threadIdx.x;
    if (i >= E_) return;
    atomicAdd(&sumdis[tcol[i]], dis_t[trow[i]]);
    int r = crow[i], c = ccol[i];
    float nrm = dis_c[r] * ew[i] * dis_c[c];
    atomicAdd(&y4[c * 4 + 0], nrm * x_car[r * 3 + 0]);
    atomicAdd(&y4[c * 4 + 1], nrm * x_car[r * 3 + 1]);
    atomicAdd(&y4[c * 4 + 2], nrm * x_car[r * 3 + 2]);
}

__global__ void k_fin(int nt, int nc,
                      const float* __restrict__ dis_t, const float* __restrict__ sumdis,
                      float* __restrict__ s_t,
                      const float* __restrict__ dis_c, const float* __restrict__ x_car,
                      float* __restrict__ y4) {
    int i = blockIdx.x * blockDim.x + threadIdx.x;
    if (i < nt) {
        float d = dis_t[i];
        s_t[i] = d * sumdis[i] + d * d;
    }
    if (i < nc) {
        float d2 = dis_c[i] * dis_c[i];
        y4[i * 4 + 0] += d2 * x_car[i * 3 + 0];
        y4[i * 4 + 1] += d2 * x_car[i * 3 + 1];
        y4[i * 4 + 2] += d2 * x_car[i * 3 + 2];
        y4[i * 4 + 3] = 1.0f;
    }
}

// ============ launch ============

extern "C" void kernel_launch(void* const* d_in, const int* in_sizes, int n_in,
                              void* d_out, int out_size, void* d_ws, size_t ws_size,
                              hipStream_t stream) {
    const float* x_car  = (const float*)d_in[0];
    const int*   ei_t   = (const int*)d_in[1];
    const int*   ei_c   = (const int*)d_in[2];
    const float* ew_c   = (const float*)d_in[3];
    const int*   src    = (const int*)d_in[4];
    const int*   dst    = (const int*)d_in[5];
    const float* W_t    = (const float*)d_in[7];
    const float* b_t    = (const float*)d_in[8];
    const float* W_c    = (const float*)d_in[9];
    const float* b_c    = (const float*)d_in[10];
    const float* W_lin  = (const float*)d_in[11];
    const float* b_lin  = (const float*)d_in[12];
    float* out = (float*)d_out;

    const int NC = in_sizes[0] / 3;   // 100000
    const int E_ = in_sizes[1] / 2;   // 1600000
    const int P_ = in_sizes[4];       // 200000

    const int* trow = ei_t;  const int* tcol = ei_t + E_;
    const int* crow = ei_c;  const int* ccol = ei_c + E_;

    char* ws = (char*)d_ws;
    int gP = (P_ + BLK - 1) / BLK;
    int chunk = (E_ + PB - 1) / PB;

    if (ws_size >= WS_NEED_NEW && chunk <= CHUNK_MAX && NB * NPB >= N_TRUCK &&
        NB * NPB >= NC && NB * CAP >= E_ + 8192) {
        int*      curT  = (int*)(ws + 0);
        int*      curC  = (int*)(ws + 1024);
        float*    G     = (float*)(ws + 2048);
        float*    dis_t = (float*)(ws + 4096);
        float*    dis_c = (float*)(ws + 404096);
        float*    s_t   = (float*)(ws + 804096);
        float*    y4    = (float*)(ws + 1204096);
        float4*   xs4   = (float4*)(ws + 2804096);
        unsigned* pT    = (unsigned*)(ws + 4404096);
        u64*      pC8   = (u64*)(ws + 12792704);

        hipMemsetAsync(ws, 0, 2048, stream);   // cursors
        k_place<<<PB + 1, BLK_PL, 0, stream>>>(trow, tcol, crow, ccol, ew_c, E_,
                                               curT, curC, pT, pC8,
                                               W_t, b_t, W_c, b_c, W_lin, G);
        k_deg2<<<2 * NB, BLK_P, 0, stream>>>(pT, pC8, curT, curC, x_car,
                                             dis_t, dis_c, xs4, N_TRUCK, NC);
        k_agg<<<2 * NB, BLK_P, 0, stream>>>(pT, pC8, curT, curC, dis_t, dis_c,
                                            xs4, s_t, (float4*)y4, N_TRUCK, NC);
        k_pairs<<<gP, BLK, 0, stream>>>(src, dst, P_, s_t, (const float4*)y4, G, b_lin, out);
    } else {
        // round-1 global-atomic fallback (~4 MB ws)
        int*   cnt_t  = (int*)(ws + 0);
        float* sumdis = (float*)(ws + 400000);
        float* degw_c = (float*)(ws + 800000);
        float* y4     = (float*)(ws + 1200000);
        float* dis_t  = (float*)(ws + 2800000);
        float* dis_c  = (float*)(ws + 3200000);
        float* s_t    = (float*)(ws + 3600000);
        float* G      = (float*)(ws + 4000000);

        hipMemsetAsync(ws, 0, 2800000, stream);
        int gE = (E_ + BLK - 1) / BLK;
        int gN = ((N_TRUCK > NC ? N_TRUCK : NC) + BLK - 1) / BLK;
        k_deg<<<gE, BLK, 0, stream>>>(tcol, ccol, ew_c, E_, cnt_t, degw_c);
        k_dis<<<gN, BLK, 0, stream>>>(cnt_t, degw_c, dis_t, dis_c, N_TRUCK, NC);
        k_scat<<<gE, BLK, 0, stream>>>(trow, tcol, crow, ccol, ew_c, E_,
                                       dis_t, dis_c, x_car, sumdis, y4);
        k_fin<<<gN, BLK, 0, stream>>>(N_TRUCK, NC, dis_t, sumdis, s_t, dis_c, x_car, y4);
        k_G<<<1, 64, 0, stream>>>(W_t, b_t, W_c, b_c, W_lin, G);
        k_pairs<<<gP, BLK, 0, stream>>>(src, dst, P_, s_t, (const float4*)y4, G, b_lin, out);
    }
}